// Round 17
// baseline (30.056 us; speedup 1.0000x reference)
//
#include <hip/hip_runtime.h>
#include <math.h>

#define N      8192
#define BLK    256
#define RPT    4                    // resident b-points per lane
#define BPW    (64 * RPT)           // 256 b-points per wave
#define NB     (N / BPW)            // 32 b-groups
#define NA     (N / 64)             // 128 a-tiles
#define GRID   ((NB * NA) / 4)      // 1024 blocks of 4 waves = 4 waves/SIMD
#define RBLK   1024

// ---------------------------------------------------- precompute + init ----
// P[0..N) = target {x,y,z,|p|^2}; P[N..2N) = output. dmin = +inf bits.
__global__ __launch_bounds__(BLK) void chamfer_prep_kernel(
        const float* __restrict__ tgt, const float* __restrict__ outp,
        float4* __restrict__ P, unsigned* __restrict__ dmin) {
    int i = blockIdx.x * BLK + (int)threadIdx.x;   // 0 .. 2N-1
    const float* src = (i < N) ? tgt : outp;
    int k = (i < N) ? i : (i - N);
    float x = src[3 * k + 0];
    float y = src[3 * k + 1];
    float z = src[3 * k + 2];
    P[i] = make_float4(x, y, z, fmaf(x, x, fmaf(y, y, z * z)));
    dmin[i] = 0x7F800000u;  // +inf
}

// ---------------------------------------------------------------- dist ----
// Register-resident systolic ring (R16 structure, verified absmax 0) at
// RPT=4: 4096 waves -> 4 waves/SIMD, enough TLP to hide the per-step
// ds_bpermute chain latency that throttled R16's 2 waves/SIMD. Lane holds
// 4 B-points; A-packet {-2x,-2y,-2z,a2,runmin} rotates through 64 lanes;
// each pair computed ONCE serving BOTH directions. Zero hot-loop memory ops.
__global__ __launch_bounds__(BLK) void chamfer_dist_kernel(
        const float4* __restrict__ P, unsigned* __restrict__ dmin) {
    int tid  = (int)threadIdx.x;
    int lane = tid & 63;
    int W    = (int)blockIdx.x * 4 + (tid >> 6);   // global wave id
    int bt   = W % NB;                             // b-group
    int at   = W / NB;                             // a-tile

    // resident B-points (output cloud), coalesced
    float bx[RPT], by[RPT], bz[RPT], b2[RPT], ca[RPT];
    #pragma unroll
    for (int k = 0; k < RPT; ++k) {
        float4 b = P[N + bt * BPW + k * 64 + lane];
        bx[k] = b.x; by[k] = b.y; bz[k] = b.z; b2[k] = b.w;
        ca[k] = __builtin_inff();
    }

    // own A-packet (target cloud)
    float4 a = P[at * 64 + lane];
    float px = -2.0f * a.x;
    float py = -2.0f * a.y;
    float pz = -2.0f * a.z;
    float pw = a.w;                       // a^2
    float pr = __builtin_inff();          // traveling row-min (d^2)
    int src = (lane + 1) & 63;            // ring: pull from lane+1

    for (int s = 0; s < 64; ++s) {
        #pragma unroll
        for (int k = 0; k < RPT; k += 2) {
            float t0 = fmaf(px, bx[k],     fmaf(py, by[k],
                       fmaf(pz, bz[k],     pw))) + b2[k];
            float t1 = fmaf(px, bx[k + 1], fmaf(py, by[k + 1],
                       fmaf(pz, bz[k + 1], pw))) + b2[k + 1];
            pr        = fminf(fminf(pr, t0), t1);   // v_min3
            ca[k]     = fminf(ca[k],     t0);
            ca[k + 1] = fminf(ca[k + 1], t1);
        }
        px = __shfl(px, src, 64);
        py = __shfl(py, src, 64);
        pz = __shfl(pz, src, 64);
        pw = __shfl(pw, src, 64);
        pr = __shfl(pr, src, 64);
    }

    // packet is home: commit row-min for a-point at*64+lane
    atomicMin(&dmin[at * 64 + lane], __float_as_uint(fmaxf(pr, 0.0f)));
    // commit resident col-mins for this wave's 256 b-points
    #pragma unroll
    for (int k = 0; k < RPT; ++k)
        atomicMin(&dmin[N + bt * BPW + k * 64 + lane],
                  __float_as_uint(fmaxf(ca[k], 0.0f)));
}

// -------------------------------------------------------------- reduce ----
__global__ __launch_bounds__(RBLK) void chamfer_reduce_kernel(
        const unsigned* __restrict__ dmin,
        const int* __restrict__ curp, const int* __restrict__ subp,
        float* __restrict__ out) {
    __shared__ float sh1[RBLK / 64], sh2[RBLK / 64];
    int t = (int)threadIdx.x;
    float s1 = 0.0f, s2 = 0.0f;
    const uint4* da = (const uint4*)dmin;          // dist1 as uint4
    const uint4* db = (const uint4*)(dmin + N);    // dist2 as uint4
    for (int i = t; i < N / 4; i += RBLK) {
        uint4 v1 = da[i], v2 = db[i];
        s1 += sqrtf(__uint_as_float(v1.x)) + sqrtf(__uint_as_float(v1.y))
            + sqrtf(__uint_as_float(v1.z)) + sqrtf(__uint_as_float(v1.w));
        s2 += sqrtf(__uint_as_float(v2.x)) + sqrtf(__uint_as_float(v2.y))
            + sqrtf(__uint_as_float(v2.z)) + sqrtf(__uint_as_float(v2.w));
    }
    #pragma unroll
    for (int off = 32; off > 0; off >>= 1) {
        s1 += __shfl_down(s1, off, 64);
        s2 += __shfl_down(s2, off, 64);
    }
    int wid = t >> 6, lane = t & 63;
    if (lane == 0) { sh1[wid] = s1; sh2[wid] = s2; }
    __syncthreads();
    if (t == 0) {
        float t1 = 0.0f, t2 = 0.0f;
        #pragma unroll
        for (int w = 0; w < RBLK / 64; ++w) { t1 += sh1[w]; t2 += sh2[w]; }
        int e = curp[0] / subp[0];
        double scale = 10.0 / pow(0.99, (double)e);
        out[0] = (float)((((double)t1 + (double)t2) / (double)N) * 0.5 * scale);
    }
}

// ---------------------------------------------------------------- launch ----
extern "C" void kernel_launch(void* const* d_in, const int* in_sizes, int n_in,
                              void* d_out, int out_size, void* d_ws, size_t ws_size,
                              hipStream_t stream) {
    const float* target = (const float*)d_in[0];   // (1, 8192, 3) f32
    const float* output = (const float*)d_in[1];   // (1, 8192, 3) f32
    const int*   curp   = (const int*)d_in[2];
    const int*   subp   = (const int*)d_in[3];
    float* out = (float*)d_out;

    // ws: float4 P[2N] (256KB) | uint dmin[2N] (64KB)
    float4*   P    = (float4*)d_ws;
    unsigned* dmin = (unsigned*)(P + 2 * N);

    chamfer_prep_kernel<<<2 * N / BLK, BLK, 0, stream>>>(target, output, P, dmin);
    chamfer_dist_kernel<<<GRID, BLK, 0, stream>>>(P, dmin);
    chamfer_reduce_kernel<<<1, RBLK, 0, stream>>>(dmin, curp, subp, out);
}

// Round 18
// 23.981 us; speedup vs baseline: 1.2533x; 1.2533x over previous
//
#include <hip/hip_runtime.h>
#include <math.h>

#define N      8192
#define BLK    256
#define RPT    8                    // resident b-points per lane
#define G      (RPT / 2)            // packed pair-groups per lane
#define BPW    (64 * RPT)           // 512 b-points per wave
#define NB     (N / BPW)            // 16 b-groups
#define NA     (N / 64)             // 128 a-tiles
#define GRID   ((NB * NA) / 4)      // 512 blocks of 4 waves
#define RBLK   1024

typedef float v2f __attribute__((ext_vector_type(2)));

// Full-wave rotate-by-1 on the VALU pipe (DPP wave_ror:1, ctrl 0x13C).
// No LDS crossbar: replaces ds_bpermute (~12 cyc LDS pipe) with ~2 cyc VALU.
// Builtin (not asm) so the compiler inserts any required DPP hazard nops.
__device__ __forceinline__ float rot1(float x) {
    return __int_as_float(__builtin_amdgcn_mov_dpp(
        __float_as_int(x), 0x13C, 0xF, 0xF, false));
}

// ---------------------------------------------------- precompute + init ----
// P[0..N) = target {x,y,z,|p|^2}; P[N..2N) = output. dmin = +inf bits.
__global__ __launch_bounds__(BLK) void chamfer_prep_kernel(
        const float* __restrict__ tgt, const float* __restrict__ outp,
        float4* __restrict__ P, unsigned* __restrict__ dmin) {
    int i = blockIdx.x * BLK + (int)threadIdx.x;   // 0 .. 2N-1
    const float* src = (i < N) ? tgt : outp;
    int k = (i < N) ? i : (i - N);
    float x = src[3 * k + 0];
    float y = src[3 * k + 1];
    float z = src[3 * k + 2];
    P[i] = make_float4(x, y, z, fmaf(x, x, fmaf(y, y, z * z)));
    dmin[i] = 0x7F800000u;  // +inf
}

// ---------------------------------------------------------------- dist ----
// Register-resident systolic ring (R16 logic, verified absmax 0), with:
//  (a) DPP wave_ror:1 rotation instead of ds_bpermute — R17 proved the ring
//      is LDS-crossbar-throughput-bound (655K->1.31M bpermutes scaled dist
//      12.8->25.6us exactly); DPP moves rotation onto the VALU at ~2cyc.
//  (b) packed v_pk_fma_f32 compute over resident point-pairs (R10's trick):
//      per 2 points = 1 pk_add + 3 pk_fma + 1 min3 + 2 min.
// Lane holds 8 B-points; A-packet {-2x,-2y,-2z,a2,runmin} rotates through
// 64 lanes; 64 steps; each pair computed ONCE serving BOTH directions.
// d^2 = a^2 + b^2 - 2 a.b, clamped at commit.
__global__ __launch_bounds__(BLK) void chamfer_dist_kernel(
        const float4* __restrict__ P, unsigned* __restrict__ dmin) {
    int tid  = (int)threadIdx.x;
    int lane = tid & 63;
    int W    = (int)blockIdx.x * 4 + (tid >> 6);   // global wave id
    int bt   = W % NB;                             // b-group
    int at   = W / NB;                             // a-tile

    // resident B-points (output cloud), packed as point-pairs
    v2f bx2[G], by2[G], bz2[G], b22[G], ca2[G];
    #pragma unroll
    for (int g = 0; g < G; ++g) {
        float4 u = P[N + bt * BPW + (2 * g)     * 64 + lane];
        float4 v = P[N + bt * BPW + (2 * g + 1) * 64 + lane];
        bx2[g] = (v2f){u.x, v.x};
        by2[g] = (v2f){u.y, v.y};
        bz2[g] = (v2f){u.z, v.z};
        b22[g] = (v2f){u.w, v.w};
        ca2[g] = (v2f){__builtin_inff(), __builtin_inff()};
    }

    // own A-packet (target cloud)
    float4 a = P[at * 64 + lane];
    float px = -2.0f * a.x;
    float py = -2.0f * a.y;
    float pz = -2.0f * a.z;
    float pw = a.w;                       // a^2
    float pr = __builtin_inff();          // traveling row-min (d^2)

    for (int s = 0; s < 64; ++s) {
        v2f px2 = {px, px}, py2 = {py, py}, pz2 = {pz, pz}, pw2 = {pw, pw};
        #pragma unroll
        for (int g = 0; g < G; ++g) {
            v2f t = __builtin_elementwise_fma(pz2, bz2[g], b22[g] + pw2);
            t     = __builtin_elementwise_fma(py2, by2[g], t);
            t     = __builtin_elementwise_fma(px2, bx2[g], t);   // full d^2
            pr     = fminf(fminf(pr, t.x), t.y);                 // v_min3
            ca2[g] = __builtin_elementwise_min(ca2[g], t);
        }
        px = rot1(px);
        py = rot1(py);
        pz = rot1(pz);
        pw = rot1(pw);
        pr = rot1(pr);
    }

    // packet is home after 64 rotations: commit row-min for a-point
    atomicMin(&dmin[at * 64 + lane], __float_as_uint(fmaxf(pr, 0.0f)));
    // commit resident col-mins for this wave's 512 b-points
    #pragma unroll
    for (int g = 0; g < G; ++g) {
        atomicMin(&dmin[N + bt * BPW + (2 * g)     * 64 + lane],
                  __float_as_uint(fmaxf(ca2[g].x, 0.0f)));
        atomicMin(&dmin[N + bt * BPW + (2 * g + 1) * 64 + lane],
                  __float_as_uint(fmaxf(ca2[g].y, 0.0f)));
    }
}

// -------------------------------------------------------------- reduce ----
__global__ __launch_bounds__(RBLK) void chamfer_reduce_kernel(
        const unsigned* __restrict__ dmin,
        const int* __restrict__ curp, const int* __restrict__ subp,
        float* __restrict__ out) {
    __shared__ float sh1[RBLK / 64], sh2[RBLK / 64];
    int t = (int)threadIdx.x;
    float s1 = 0.0f, s2 = 0.0f;
    const uint4* da = (const uint4*)dmin;          // dist1 as uint4
    const uint4* db = (const uint4*)(dmin + N);    // dist2 as uint4
    for (int i = t; i < N / 4; i += RBLK) {
        uint4 v1 = da[i], v2 = db[i];
        s1 += sqrtf(__uint_as_float(v1.x)) + sqrtf(__uint_as_float(v1.y))
            + sqrtf(__uint_as_float(v1.z)) + sqrtf(__uint_as_float(v1.w));
        s2 += sqrtf(__uint_as_float(v2.x)) + sqrtf(__uint_as_float(v2.y))
            + sqrtf(__uint_as_float(v2.z)) + sqrtf(__uint_as_float(v2.w));
    }
    #pragma unroll
    for (int off = 32; off > 0; off >>= 1) {
        s1 += __shfl_down(s1, off, 64);
        s2 += __shfl_down(s2, off, 64);
    }
    int wid = t >> 6, lane = t & 63;
    if (lane == 0) { sh1[wid] = s1; sh2[wid] = s2; }
    __syncthreads();
    if (t == 0) {
        float t1 = 0.0f, t2 = 0.0f;
        #pragma unroll
        for (int w = 0; w < RBLK / 64; ++w) { t1 += sh1[w]; t2 += sh2[w]; }
        int e = curp[0] / subp[0];
        double scale = 10.0 / pow(0.99, (double)e);
        out[0] = (float)((((double)t1 + (double)t2) / (double)N) * 0.5 * scale);
    }
}

// ---------------------------------------------------------------- launch ----
extern "C" void kernel_launch(void* const* d_in, const int* in_sizes, int n_in,
                              void* d_out, int out_size, void* d_ws, size_t ws_size,
                              hipStream_t stream) {
    const float* target = (const float*)d_in[0];   // (1, 8192, 3) f32
    const float* output = (const float*)d_in[1];   // (1, 8192, 3) f32
    const int*   curp   = (const int*)d_in[2];
    const int*   subp   = (const int*)d_in[3];
    float* out = (float*)d_out;

    // ws: float4 P[2N] (256KB) | uint dmin[2N] (64KB)
    float4*   P    = (float4*)d_ws;
    unsigned* dmin = (unsigned*)(P + 2 * N);

    chamfer_prep_kernel<<<2 * N / BLK, BLK, 0, stream>>>(target, output, P, dmin);
    chamfer_dist_kernel<<<GRID, BLK, 0, stream>>>(P, dmin);
    chamfer_reduce_kernel<<<1, RBLK, 0, stream>>>(dmin, curp, subp, out);
}